// Round 3
// baseline (6568.880 us; speedup 1.0000x reference)
//
#include <hip/hip_runtime.h>
#include <hip/hip_bf16.h>
#include <cstdio>
#include <cstdint>

// MultilayerGRU: B=32, S=512, I=H=O=1024, L=2
// R7: fused two-layer pipeline, v3 — 4 waves/block.
//  R6 post-mortem: VGPR_Count=256 is the addressable-VGPR encoding cap;
//  layer1's path (wzr 128 + wg 64 + wgx 64 = 256 weight regs) overflowed
//  into AGPR shuffles/scratch inside the MFMA loops -> 12.2 us/step.
//  Fix: 256 threads/block, gate-parts/K-ranges split one-per-wave:
//   L1 stage1: w0=z.rec w1=r.rec w2=z.x w3=r.x (32 MFMA, 128 weight VGPRs
//   each); stage2: g split 4 ways (64 VGPRs each). Worst case ~192 weight
//   regs/wave -> fits cleanly. Waves 2-3 drop f32 partials in LDS; waves
//   0-1 finalize. L0 gets the same shape via K-splits. WXZ LDS buffer gone.
//   Poll-gating makes the post-finalize and loop-bottom barriers redundant
//   -> 4 barriers/step.

typedef float f32x4 __attribute__((ext_vector_type(4)));
typedef __bf16 bf16x8 __attribute__((ext_vector_type(8)));
typedef unsigned short u16;

#define AS1 __attribute__((address_space(1)))
#define AS3 __attribute__((address_space(3)))

__device__ inline u16 f2b(float f) {
  __hip_bfloat16 h = __float2bfloat16(f);
  return *reinterpret_cast<u16*>(&h);
}
__device__ inline float b2f(u16 u) {
  __hip_bfloat16 h;
  *reinterpret_cast<u16*>(&h) = u;
  return __bfloat162float(h);
}
__device__ inline bf16x8 ld8(const u16* p) {
  return *reinterpret_cast<const bf16x8*>(p);
}
__device__ inline f32x4 mfma16(bf16x8 a, bf16x8 b, f32x4 c) {
  return __builtin_amdgcn_mfma_f32_16x16x32_bf16(a, b, c, 0, 0, 0);
}

// plain (L2-cacheable) global->LDS DMA, 16B/lane
__device__ inline void gload_lds16(const void* g, void* l) {
  __builtin_amdgcn_global_load_lds((const AS1 void*)g, (AS3 void*)l, 16, 0, 0);
}
// agent-scope global->LDS DMA (CPol SC1 only = device scope): bypasses the
// potentially-stale per-XCD L2 but is served by the LLC (agent coherence pt).
__device__ inline void gload_lds16c(const void* g, void* l) {
  __builtin_amdgcn_global_load_lds((const AS1 void*)g, (AS3 void*)l, 16, 0, 0x10);
}

// relaxed agent-scope (LLC write-through) u16 store
__device__ inline void st16(u16* p, u16 v) {
  __hip_atomic_store(p, v, __ATOMIC_RELAXED, __HIP_MEMORY_SCOPE_AGENT);
}

// 64 lanes watch 64 packed epoch flags; exit when all >= target
__device__ inline void poll64(unsigned* f, unsigned target, int lane) {
  unsigned* p = f + lane;
  while (true) {
    unsigned v = __hip_atomic_load(p, __ATOMIC_RELAXED, __HIP_MEMORY_SCOPE_AGENT);
    if (__all((int)(v >= target))) break;
    __builtin_amdgcn_s_sleep(1);
  }
}

// combined two-flag-array poll (one LLC round trip for both conditions)
__device__ inline void poll64x2(unsigned* fa, unsigned ta, unsigned* fb,
                                unsigned tb, int lane) {
  unsigned* pa = fa + lane;
  unsigned* pb = fb + lane;
  while (true) {
    unsigned va = __hip_atomic_load(pa, __ATOMIC_RELAXED, __HIP_MEMORY_SCOPE_AGENT);
    unsigned vb = __hip_atomic_load(pb, __ATOMIC_RELAXED, __HIP_MEMORY_SCOPE_AGENT);
    if (__all((int)(va >= ta) & (int)(vb >= tb))) break;
    __builtin_amdgcn_s_sleep(1);
  }
}

// ---------------- elementwise helpers ----------------

__global__ void castk(const float* __restrict__ src, u16* __restrict__ dst, int n) {
  int i = blockIdx.x * 256 + threadIdx.x;
  if (i < n) dst[i] = f2b(src[i]);
}

__global__ void init_h(const float* __restrict__ h0, float* __restrict__ h32_0,
                       float* __restrict__ h32_1, u16* __restrict__ hring_s3,
                       u16* __restrict__ hbf_1) {
  int i = blockIdx.x * 256 + threadIdx.x;
  if (i < 32 * 1024) {
    int b = i >> 10, j = i & 1023;
    float v0 = h0[(b * 2 + 0) * 1024 + j];
    float v1 = h0[(b * 2 + 1) * 1024 + j];
    h32_0[i] = v0; hring_s3[i] = f2b(v0);  // layer0 h(-1) lives in ring slot 3
    h32_1[i] = v1; hbf_1[i] = f2b(v1);
  }
}

__global__ void final_h(const float* __restrict__ h32_0, const float* __restrict__ h32_1,
                        float* __restrict__ out) {
  int i = blockIdx.x * 256 + threadIdx.x;
  if (i < 32 * 1024) {
    int b = i >> 10, j = i & 1023;
    out[(b * 2 + 0) * 1024 + j] = h32_0[i];
    out[(b * 2 + 1) * 1024 + j] = h32_1[i];
  }
}

// ---------------- big NT GEMM: C[m,n] = sum_k A[m,k]*B[n,k] + bias[n] ----------------
// MODE 0: fp32 store at [m][n].  MODE 2: bf16 store transposed-to-step-major:
// m = b*512 + t  ->  store at [(t*32 + b)][n]  (A buffers for the recurrence).

template <int MODE>
__global__ __launch_bounds__(256, 2) void gemm_nt(const u16* __restrict__ A,
                                                  const u16* __restrict__ B,
                                                  const float* __restrict__ bias,
                                                  void* __restrict__ Cout,
                                                  int M, int N, int K) {
  __shared__ __align__(16) u16 As[128 * 32];
  __shared__ __align__(16) u16 Bs[128 * 32];
  const int tid = threadIdx.x;
  const int lane = tid & 63;
  const int wave = tid >> 6;
  const int tilesN = N >> 7;
  const int bm = blockIdx.x / tilesN, bn = blockIdx.x % tilesN;
  const int wr = (wave >> 1) << 6, wc = (wave & 1) << 6;
  const int la = lane & 15, kg = lane >> 4;
  f32x4 acc[4][4] = {};
  const int srow = tid >> 2, skoff = (tid & 3) << 3;
  const u16* Ap = A + (size_t)(bm * 128 + srow) * K + skoff;
  const u16* Bp = B + (size_t)(bn * 128 + srow) * K + skoff;
  for (int k0 = 0; k0 < K; k0 += 32) {
    gload_lds16(Ap + k0,            As + tid * 8);
    gload_lds16(Ap + (size_t)64 * K + k0, As + 2048 + tid * 8);
    gload_lds16(Bp + k0,            Bs + tid * 8);
    gload_lds16(Bp + (size_t)64 * K + k0, Bs + 2048 + tid * 8);
    __syncthreads();
    bf16x8 af[4], bfr[4];
#pragma unroll
    for (int i = 0; i < 4; ++i) af[i] = ld8(As + (wr + i * 16 + la) * 32 + kg * 8);
#pragma unroll
    for (int j = 0; j < 4; ++j) bfr[j] = ld8(Bs + (wc + j * 16 + la) * 32 + kg * 8);
#pragma unroll
    for (int i = 0; i < 4; ++i)
#pragma unroll
      for (int j = 0; j < 4; ++j)
        acc[i][j] = mfma16(af[i], bfr[j], acc[i][j]);
    __syncthreads();
  }
  const int rbase = bm * 128 + wr + kg * 4;
  const int cbase = bn * 128 + wc + la;
#pragma unroll
  for (int i = 0; i < 4; ++i) {
#pragma unroll
    for (int j = 0; j < 4; ++j) {
      int col = cbase + j * 16;
      float bv = bias[col];
#pragma unroll
      for (int e = 0; e < 4; ++e) {
        int row = rbase + i * 16 + e;
        float v = acc[i][j][e] + bv;
        if (MODE == 0) {
          ((float*)Cout)[(size_t)row * N + col] = v;
        } else {
          int tt = row & 511, bb = row >> 9;
          ((u16*)Cout)[((size_t)(tt * 32 + bb)) * N + col] = f2b(v);
        }
      }
    }
  }
}

// ---------------- fused two-layer persistent GRU recurrence, v3 ----------------
// 256 blocks x 256 threads (4 waves): layer = bid>>7, rt=(bid>>6)&1, colT=bid&63.
// Stage1: waves {0,2} = z, waves {1,3} = r. L0: K-split (w>>1 = K-half);
//   L1: w0/w1 = recurrent (LDSh), w2/w3 = x-projection of h0(t) (LDSx).
//   Waves 2-3 write f32 partials to LDS; wave0 finalizes z, wave1 finalizes
//   r (st16 rhbf + drain + fl1).
// Stage2: g split 4 ways. L0: K-quarters of Wg0; L1: w0/w1 = Wg1 K-halves
//   (LDSh=rh), w2/w3 = Wgx1 K-halves (LDSx=h0, still valid from stage1).
//   Waves 1-3 write partials; wave0 finalizes h (st16 + drain + fl2).
// Ring: layer0 h -> hring[4] slots; fl2(L0) is the cross-layer flag; layer0
//   gates on fl1(L1) >= t-3 so a slot is never overwritten early.

__global__ __launch_bounds__(256, 1) void gru_pipe3(
    const u16* __restrict__ Wz0, const u16* __restrict__ Wr0, const u16* __restrict__ Wg0,
    const u16* __restrict__ Wz1, const u16* __restrict__ Wr1, const u16* __restrict__ Wg1,
    const u16* __restrict__ Wzx1, const u16* __restrict__ Wrx1, const u16* __restrict__ Wgx1,
    const float* __restrict__ bz1, const float* __restrict__ br1, const float* __restrict__ bg1,
    const u16* __restrict__ Az, const u16* __restrict__ Ar, const u16* __restrict__ Ag,
    u16* __restrict__ hring, u16* __restrict__ hist1,
    float* __restrict__ h32_0, float* __restrict__ h32_1,
    u16* __restrict__ hbf1,
    u16* __restrict__ rhbf0, u16* __restrict__ rhbf1,
    unsigned* __restrict__ flags, int S) {
  __shared__ __align__(16) u16 LDSh[16 * 1024];
  __shared__ __align__(16) u16 LDSx[16 * 1024];
  __shared__ float part[4][256];
  __shared__ float zloc[256];
  __shared__ float h32loc[256];
  const int tid = threadIdx.x, wave = tid >> 6, lane = tid & 63;
  const int la = lane & 15, kg = lane >> 4;
  const int sw = la & 7;
  const int layer = blockIdx.x >> 7;
  const int rt = (blockIdx.x >> 6) & 1, colT = blockIdx.x & 63;
  const int col = colT * 16 + la;
  unsigned* myfl1 = flags + (layer * 2 + rt) * 128;  // stage1 (rhbf ready)
  unsigned* myfl2 = myfl1 + 64;                      // stage2 (h ready)
  unsigned* l1fl1 = flags + (2 + rt) * 128;          // layer1 stage1 (ring consumed)
  unsigned* l0fl2 = flags + rt * 128 + 64;           // layer0 h ready

  float* h32g = layer ? h32_1 : h32_0;
  u16* rhbf = layer ? rhbf1 : rhbf0;

  h32loc[tid] = h32g[(rt * 16 + (tid >> 4)) * 1024 + colT * 16 + (tid & 15)];

  // ---- stage-1 weights -> VGPRs ----
  bf16x8 wzr[32];
  if (layer) {
    const u16* wsrc;
    if (wave == 0) wsrc = Wz1;
    else if (wave == 1) wsrc = Wr1;
    else if (wave == 2) wsrc = Wzx1;
    else wsrc = Wrx1;
    const u16* wp = wsrc + (size_t)col * 1024 + kg * 8;
#pragma unroll
    for (int ks = 0; ks < 32; ++ks) wzr[ks] = ld8(wp + ks * 32);
  } else {
    const u16* wsrc = (wave & 1) ? Wr0 : Wz0;
    const u16* wp = wsrc + (size_t)col * 1024 + kg * 8 + (size_t)(wave >> 1) * 512;
#pragma unroll
    for (int ks = 0; ks < 16; ++ks) wzr[ks] = ld8(wp + ks * 32);
  }
  // ---- stage-2 weights -> VGPRs ----
  bf16x8 wg[16];
  if (layer) {
    const u16* wsrc = (wave < 2) ? Wg1 : Wgx1;
    const u16* wp = wsrc + (size_t)col * 1024 + kg * 8 + (size_t)(wave & 1) * 512;
#pragma unroll
    for (int ks = 0; ks < 16; ++ks) wg[ks] = ld8(wp + ks * 32);
  } else {
    const u16* wp = Wg0 + (size_t)col * 1024 + kg * 8 + (size_t)wave * 256;
#pragma unroll
    for (int ks = 0; ks < 8; ++ks) wg[ks] = ld8(wp + ks * 32);
  }
  float b1v = 0.f, bgv = 0.f;
  if (layer) {
    if (wave == 0) { b1v = bz1[col]; bgv = bg1[col]; }
    else if (wave == 1) b1v = br1[col];
  }
  __syncthreads();  // h32loc staged

  const u16* A1 = (wave == 1) ? Ar : Az;
  const u16* rsrc = rhbf + rt * 16384;
  const int rowb = rt * 16 + kg * 4;  // batch-row base of this lane's outputs

  for (int t = 0; t < S; ++t) {
    u16 a1raw[4] = {0, 0, 0, 0};
    u16 agraw[4] = {0, 0, 0, 0};
    if (!layer) {
      // A prefetch: independent of flags, overlaps poll+staging
      if (wave < 2) {
        const u16* A1t = A1 + (size_t)t * 32768;
#pragma unroll
        for (int e = 0; e < 4; ++e) a1raw[e] = A1t[(rowb + e) * 1024 + col];
      }
      if (wave == 0) {
        const u16* Agt = Ag + (size_t)t * 32768;
#pragma unroll
        for (int e = 0; e < 4; ++e) agraw[e] = Agt[(rowb + e) * 1024 + col];
      }
      // own h(t-1) ready + ring slot t&3 free (layer1 staged step t-4)
      unsigned tb = t >= 4 ? (unsigned)(t - 3) : 0u;
      poll64x2(myfl2, (unsigned)t, l1fl1, tb, lane);
    } else {
      // h1(t-1) ready + h0(t) ready; then both tiles' DMAs back-to-back
      poll64x2(myfl2, (unsigned)t, l0fl2, (unsigned)(t + 1), lane);
      const u16* xs = hring + (t & 3) * 32768 + rt * 16384;
#pragma unroll
      for (int i = 0; i < 8; ++i) {
        int u = i * 4 + wave, r = u >> 1, c = u & 1;
        gload_lds16c(xs + r * 1024 + c * 512 + (lane ^ (r & 7)) * 8,
                     LDSx + r * 1024 + c * 512 + lane * 8);
      }
    }
    // ---- stage 1 staging: h(t-1) -> LDSh (all 4 waves) ----
    const u16* hs = layer ? (hbf1 + rt * 16384)
                          : (hring + ((t + 3) & 3) * 32768 + rt * 16384);
#pragma unroll
    for (int i = 0; i < 8; ++i) {
      int u = i * 4 + wave, r = u >> 1, c = u & 1;
      gload_lds16c(hs + r * 1024 + c * 512 + (lane ^ (r & 7)) * 8,
                   LDSh + r * 1024 + c * 512 + lane * 8);
    }
    __syncthreads();  // B1: all DMA drained
    // ---- stage 1 MFMA ----
    f32x4 p0 = {0.f, 0.f, 0.f, 0.f}, p1 = {0.f, 0.f, 0.f, 0.f};
    if (layer) {
      const u16* aB = (wave >= 2) ? LDSx : LDSh;
#pragma unroll
      for (int ks = 0; ks < 32; ks += 2) {
        p0 = mfma16(ld8(aB + la * 1024 + (((ks * 4 + kg) ^ sw) << 3)), wzr[ks], p0);
        p1 = mfma16(ld8(aB + la * 1024 + ((((ks + 1) * 4 + kg) ^ sw) << 3)), wzr[ks + 1], p1);
      }
    } else {
      const int ko = (wave >> 1) * 16;
#pragma unroll
      for (int ks = 0; ks < 16; ks += 2) {
        p0 = mfma16(ld8(LDSh + la * 1024 + ((((ko + ks) * 4 + kg) ^ sw) << 3)), wzr[ks], p0);
        p1 = mfma16(ld8(LDSh + la * 1024 + ((((ko + ks + 1) * 4 + kg) ^ sw) << 3)), wzr[ks + 1], p1);
      }
    }
    if (wave >= 2) {
#pragma unroll
      for (int e = 0; e < 4; ++e) part[wave][lane * 4 + e] = p0[e] + p1[e];
    }
    __syncthreads();  // B2: stage1 partials visible; all LDSh reads done
    if (wave == 0) {
#pragma unroll
      for (int e = 0; e < 4; ++e) {
        float pre = p0[e] + p1[e] + part[2][lane * 4 + e] +
                    (layer ? b1v : b2f(a1raw[e]));
        zloc[(kg * 4 + e) * 16 + la] = 1.f / (1.f + __expf(-pre));
      }
    } else if (wave == 1) {
#pragma unroll
      for (int e = 0; e < 4; ++e) {
        float pre = p0[e] + p1[e] + part[3][lane * 4 + e] +
                    (layer ? b1v : b2f(a1raw[e]));
        float rv = 1.f / (1.f + __expf(-pre));
        st16(&rhbf[(rowb + e) * 1024 + col], f2b(rv * h32loc[(kg * 4 + e) * 16 + la]));
      }
      __builtin_amdgcn_s_waitcnt(0);  // r-tile drained to LLC
      if (lane == 0)
        __hip_atomic_store(&myfl1[colT], (unsigned)(t + 1), __ATOMIC_RELAXED,
                           __HIP_MEMORY_SCOPE_AGENT);
    }
    // ---- stage 2: rh -> LDSh, then g (4-way split) + h update ----
    poll64(myfl1, (unsigned)(t + 1), lane);
#pragma unroll
    for (int i = 0; i < 8; ++i) {
      int u = i * 4 + wave, r = u >> 1, c = u & 1;
      gload_lds16c(rsrc + r * 1024 + c * 512 + (lane ^ (r & 7)) * 8,
                   LDSh + r * 1024 + c * 512 + lane * 8);
    }
    __syncthreads();  // B3: rh staged (LDSx untouched, still h0(t))
    f32x4 q0 = {0.f, 0.f, 0.f, 0.f}, q1 = {0.f, 0.f, 0.f, 0.f};
    if (layer) {
      const u16* aB = (wave >= 2) ? LDSx : LDSh;
      const int ko = (wave & 1) * 16;
#pragma unroll
      for (int ks = 0; ks < 16; ks += 2) {
        q0 = mfma16(ld8(aB + la * 1024 + ((((ko + ks) * 4 + kg) ^ sw) << 3)), wg[ks], q0);
        q1 = mfma16(ld8(aB + la * 1024 + ((((ko + ks + 1) * 4 + kg) ^ sw) << 3)), wg[ks + 1], q1);
      }
    } else {
      const int ko = wave * 8;
#pragma unroll
      for (int ks = 0; ks < 8; ks += 2) {
        q0 = mfma16(ld8(LDSh + la * 1024 + ((((ko + ks) * 4 + kg) ^ sw) << 3)), wg[ks], q0);
        q1 = mfma16(ld8(LDSh + la * 1024 + ((((ko + ks + 1) * 4 + kg) ^ sw) << 3)), wg[ks + 1], q1);
      }
    }
    if (wave != 0) {
#pragma unroll
      for (int e = 0; e < 4; ++e) part[wave][lane * 4 + e] = q0[e] + q1[e];
    }
    __syncthreads();  // B4: stage2 partials visible; all LDSh/LDSx reads done
    if (wave == 0) {
      float hnv[4];
      u16 hbv[4];
      u16* hdst = layer ? hbf1 : (hring + (t & 3) * 32768);
#pragma unroll
      for (int e = 0; e < 4; ++e) {
        int li = (kg * 4 + e) * 16 + la;
        int pi = lane * 4 + e;
        float gs = q0[e] + q1[e] + part[1][pi] + part[2][pi] + part[3][pi] +
                   (layer ? bgv : b2f(agraw[e]));
        float ex = __expf(2.f * gs);
        float g = 1.f - 2.f / (ex + 1.f);  // tanh, inf-safe
        float z = zloc[li];
        float hn = (1.f - z) * h32loc[li] + z * g;
        h32loc[li] = hn;
        hnv[e] = hn;
        hbv[e] = f2b(hn);
        st16(&hdst[(rowb + e) * 1024 + col], hbv[e]);  // critical-path publish
      }
      __builtin_amdgcn_s_waitcnt(0);  // h-tile drained to LLC
      if (lane == 0)
        __hip_atomic_store(&myfl2[colT], (unsigned)(t + 1), __ATOMIC_RELAXED,
                           __HIP_MEMORY_SCOPE_AGENT);
      // off-critical-path: layer1 history (read only by the output GEMM;
      // kernel-boundary flush provides visibility) + final-state snapshot
#pragma unroll
      for (int e = 0; e < 4; ++e) {
        if (layer) hist1[((size_t)(rowb + e) * S + t) * 1024 + col] = hbv[e];
        if (t == S - 1) h32g[(rowb + e) * 1024 + col] = hnv[e];
      }
    }
    // no loop-bottom barrier: next-step staging is gated by poll(myfl2 >= t+1),
    // which wave0 publishes only after all its LDS reads of this step.
  }
}

// ---------------- host ----------------

extern "C" void kernel_launch(void* const* d_in, const int* in_sizes, int n_in,
                              void* d_out, int out_size, void* d_ws, size_t ws_size,
                              hipStream_t stream) {
  (void)in_sizes; (void)n_in; (void)out_size;
  const float* x   = (const float*)d_in[0];
  const float* h0  = (const float*)d_in[1];
  const float* Wzx = (const float*)d_in[2];
  const float* bz  = (const float*)d_in[3];
  const float* Wzh = (const float*)d_in[4];
  const float* Wrx = (const float*)d_in[5];
  const float* br  = (const float*)d_in[6];
  const float* Wrh = (const float*)d_in[7];
  const float* Wgx = (const float*)d_in[8];
  const float* bg  = (const float*)d_in[9];
  const float* Wgh = (const float*)d_in[10];
  const float* Wo  = (const float*)d_in[11];
  const float* bo  = (const float*)d_in[12];
  float* out = (float*)d_out;
  char* ws = (char*)d_ws;

  const size_t MB = 1024 * 1024;
  size_t o = 4096;  // flags live in [0,4096): per-(layer,rt) fl1/fl2
  u16* wWzx = (u16*)(ws + o); o += 4 * MB;   // [L=2][1024][1024] bf16
  u16* wWzh = (u16*)(ws + o); o += 4 * MB;
  u16* wWrx = (u16*)(ws + o); o += 4 * MB;
  u16* wWrh = (u16*)(ws + o); o += 4 * MB;
  u16* wWgx = (u16*)(ws + o); o += 4 * MB;
  u16* wWgh = (u16*)(ws + o); o += 4 * MB;
  u16* wWo  = (u16*)(ws + o); o += 2 * MB;
  u16* Az    = (u16*)(ws + o); o += 32 * MB;  // [512][32][1024] bf16 step-major
  u16* Ar    = (u16*)(ws + o); o += 32 * MB;
  u16* Ag    = (u16*)(ws + o); o += 32 * MB;
  u16* hring = (u16*)(ws + o); o += 256 * 1024;  // [4][32][1024] layer0 h ring
  u16* xbf   = (u16*)(ws + o); o += 32 * MB;  // x bf16; later reused as hist1
  float* h32_0 = (float*)(ws + o); o += 131072;
  float* h32_1 = (float*)(ws + o); o += 131072;
  u16* hbf_1 = (u16*)(ws + o); o += 65536;
  u16* rhbf0 = (u16*)(ws + o); o += 65536;
  u16* rhbf1 = (u16*)(ws + o); o += 65536;

  if (ws_size < o) {
    fprintf(stderr, "[gru] INSUFFICIENT WORKSPACE ws=%zu need=%zu\n", ws_size, o);
    return;
  }
  unsigned* flags = (unsigned*)ws;
  hipMemsetAsync(ws, 0, 4096, stream);

  // casts
  castk<<<dim3(8192), dim3(256), 0, stream>>>(Wzx, wWzx, 2097152);
  castk<<<dim3(8192), dim3(256), 0, stream>>>(Wzh, wWzh, 2097152);
  castk<<<dim3(8192), dim3(256), 0, stream>>>(Wrx, wWrx, 2097152);
  castk<<<dim3(8192), dim3(256), 0, stream>>>(Wrh, wWrh, 2097152);
  castk<<<dim3(8192), dim3(256), 0, stream>>>(Wgx, wWgx, 2097152);
  castk<<<dim3(8192), dim3(256), 0, stream>>>(Wgh, wWgh, 2097152);
  castk<<<dim3(4096), dim3(256), 0, stream>>>(Wo, wWo, 1048576);
  castk<<<dim3(65536), dim3(256), 0, stream>>>(x, xbf, 16777216);
  init_h<<<dim3(128), dim3(256), 0, stream>>>(h0, h32_0, h32_1,
                                              hring + 3 * 32768, hbf_1);

  // layer0 input projections (step-major output)
  gemm_nt<2><<<dim3(1024), dim3(256), 0, stream>>>(xbf, wWzx, bz, Az, 16384, 1024, 1024);
  gemm_nt<2><<<dim3(1024), dim3(256), 0, stream>>>(xbf, wWrx, br, Ar, 16384, 1024, 1024);
  gemm_nt<2><<<dim3(1024), dim3(256), 0, stream>>>(xbf, wWgx, bg, Ag, 16384, 1024, 1024);

  // fused two-layer recurrence pipeline (hist1 lives in xbf region)
  gru_pipe3<<<dim3(256), dim3(256), 0, stream>>>(
      wWzh, wWrh, wWgh,
      wWzh + 1048576, wWrh + 1048576, wWgh + 1048576,
      wWzx + 1048576, wWrx + 1048576, wWgx + 1048576,
      bz + 1024, br + 1024, bg + 1024,
      Az, Ar, Ag, hring, xbf,
      h32_0, h32_1, hbf_1, rhbf0, rhbf1,
      flags, 512);

  // output projection
  gemm_nt<0><<<dim3(1024), dim3(256), 0, stream>>>(xbf, wWo, bo, out, 16384, 1024, 1024);

  // final hidden states
  final_h<<<dim3(128), dim3(256), 0, stream>>>(h32_0, h32_1, out + 16777216);
}

// Round 4
// 5260.779 us; speedup vs baseline: 1.2487x; 1.2487x over previous
//
#include <hip/hip_runtime.h>
#include <hip/hip_bf16.h>
#include <cstdio>
#include <cstdint>

// MultilayerGRU: B=32, S=512, I=H=O=1024, L=2
// R8: sync-path polish of the fused two-layer pipeline.
//  R7 post-mortem: cadence (12.2 us/step) is pure exchange-chain latency
//  (~6 serialized LLC RTTs/step); compute/register changes were neutral.
//  This round shortens the exchange legs without touching the skeleton:
//   - critical-path h / rh publishes go through a 16x16 LDS transpose so
//     each lane stores one aligned 8B dwordx2 (1 coalesced store instr vs
//     4 scattered 2B instrs inside the drain window); hist1 also coalesced.
//   - epoch flags shrink to u16 (poll footprint 2 lines, was 4).

typedef float f32x4 __attribute__((ext_vector_type(4)));
typedef __bf16 bf16x8 __attribute__((ext_vector_type(8)));
typedef unsigned short u16;
typedef unsigned long long u64;

#define AS1 __attribute__((address_space(1)))
#define AS3 __attribute__((address_space(3)))

__device__ inline u16 f2b(float f) {
  __hip_bfloat16 h = __float2bfloat16(f);
  return *reinterpret_cast<u16*>(&h);
}
__device__ inline float b2f(u16 u) {
  __hip_bfloat16 h;
  *reinterpret_cast<u16*>(&h) = u;
  return __bfloat162float(h);
}
__device__ inline bf16x8 ld8(const u16* p) {
  return *reinterpret_cast<const bf16x8*>(p);
}
__device__ inline f32x4 mfma16(bf16x8 a, bf16x8 b, f32x4 c) {
  return __builtin_amdgcn_mfma_f32_16x16x32_bf16(a, b, c, 0, 0, 0);
}

// plain (L2-cacheable) global->LDS DMA, 16B/lane
__device__ inline void gload_lds16(const void* g, void* l) {
  __builtin_amdgcn_global_load_lds((const AS1 void*)g, (AS3 void*)l, 16, 0, 0);
}
// agent-scope global->LDS DMA (CPol SC1 only = device scope): bypasses the
// potentially-stale per-XCD L2 but is served by the LLC (agent coherence pt).
__device__ inline void gload_lds16c(const void* g, void* l) {
  __builtin_amdgcn_global_load_lds((const AS1 void*)g, (AS3 void*)l, 16, 0, 0x10);
}

// relaxed agent-scope (LLC write-through) stores
__device__ inline void st16(u16* p, u16 v) {
  __hip_atomic_store(p, v, __ATOMIC_RELAXED, __HIP_MEMORY_SCOPE_AGENT);
}
__device__ inline void st64(u64* p, u64 v) {
  __hip_atomic_store(p, v, __ATOMIC_RELAXED, __HIP_MEMORY_SCOPE_AGENT);
}

// 64 lanes watch 64 packed u16 epoch flags; exit when all >= target
__device__ inline void poll64(u16* f, unsigned target, int lane) {
  u16* p = f + lane;
  while (true) {
    unsigned v = __hip_atomic_load(p, __ATOMIC_RELAXED, __HIP_MEMORY_SCOPE_AGENT);
    if (__all((int)(v >= target))) break;
    __builtin_amdgcn_s_sleep(1);
  }
}

// combined two-flag-array poll (one round trip for both conditions)
__device__ inline void poll64x2(u16* fa, unsigned ta, u16* fb, unsigned tb,
                                int lane) {
  u16* pa = fa + lane;
  u16* pb = fb + lane;
  while (true) {
    unsigned va = __hip_atomic_load(pa, __ATOMIC_RELAXED, __HIP_MEMORY_SCOPE_AGENT);
    unsigned vb = __hip_atomic_load(pb, __ATOMIC_RELAXED, __HIP_MEMORY_SCOPE_AGENT);
    if (__all((int)(va >= ta) & (int)(vb >= tb))) break;
    __builtin_amdgcn_s_sleep(1);
  }
}

// ---------------- elementwise helpers ----------------

__global__ void castk(const float* __restrict__ src, u16* __restrict__ dst, int n) {
  int i = blockIdx.x * 256 + threadIdx.x;
  if (i < n) dst[i] = f2b(src[i]);
}

__global__ void init_h(const float* __restrict__ h0, float* __restrict__ h32_0,
                       float* __restrict__ h32_1, u16* __restrict__ hring_s3,
                       u16* __restrict__ hbf_1) {
  int i = blockIdx.x * 256 + threadIdx.x;
  if (i < 32 * 1024) {
    int b = i >> 10, j = i & 1023;
    float v0 = h0[(b * 2 + 0) * 1024 + j];
    float v1 = h0[(b * 2 + 1) * 1024 + j];
    h32_0[i] = v0; hring_s3[i] = f2b(v0);  // layer0 h(-1) lives in ring slot 3
    h32_1[i] = v1; hbf_1[i] = f2b(v1);
  }
}

__global__ void final_h(const float* __restrict__ h32_0, const float* __restrict__ h32_1,
                        float* __restrict__ out) {
  int i = blockIdx.x * 256 + threadIdx.x;
  if (i < 32 * 1024) {
    int b = i >> 10, j = i & 1023;
    out[(b * 2 + 0) * 1024 + j] = h32_0[i];
    out[(b * 2 + 1) * 1024 + j] = h32_1[i];
  }
}

// ---------------- big NT GEMM: C[m,n] = sum_k A[m,k]*B[n,k] + bias[n] ----------------
// MODE 0: fp32 store at [m][n].  MODE 2: bf16 store transposed-to-step-major:
// m = b*512 + t  ->  store at [(t*32 + b)][n]  (A buffers for the recurrence).

template <int MODE>
__global__ __launch_bounds__(256, 2) void gemm_nt(const u16* __restrict__ A,
                                                  const u16* __restrict__ B,
                                                  const float* __restrict__ bias,
                                                  void* __restrict__ Cout,
                                                  int M, int N, int K) {
  __shared__ __align__(16) u16 As[128 * 32];
  __shared__ __align__(16) u16 Bs[128 * 32];
  const int tid = threadIdx.x;
  const int lane = tid & 63;
  const int wave = tid >> 6;
  const int tilesN = N >> 7;
  const int bm = blockIdx.x / tilesN, bn = blockIdx.x % tilesN;
  const int wr = (wave >> 1) << 6, wc = (wave & 1) << 6;
  const int la = lane & 15, kg = lane >> 4;
  f32x4 acc[4][4] = {};
  const int srow = tid >> 2, skoff = (tid & 3) << 3;
  const u16* Ap = A + (size_t)(bm * 128 + srow) * K + skoff;
  const u16* Bp = B + (size_t)(bn * 128 + srow) * K + skoff;
  for (int k0 = 0; k0 < K; k0 += 32) {
    gload_lds16(Ap + k0,            As + tid * 8);
    gload_lds16(Ap + (size_t)64 * K + k0, As + 2048 + tid * 8);
    gload_lds16(Bp + k0,            Bs + tid * 8);
    gload_lds16(Bp + (size_t)64 * K + k0, Bs + 2048 + tid * 8);
    __syncthreads();
    bf16x8 af[4], bfr[4];
#pragma unroll
    for (int i = 0; i < 4; ++i) af[i] = ld8(As + (wr + i * 16 + la) * 32 + kg * 8);
#pragma unroll
    for (int j = 0; j < 4; ++j) bfr[j] = ld8(Bs + (wc + j * 16 + la) * 32 + kg * 8);
#pragma unroll
    for (int i = 0; i < 4; ++i)
#pragma unroll
      for (int j = 0; j < 4; ++j)
        acc[i][j] = mfma16(af[i], bfr[j], acc[i][j]);
    __syncthreads();
  }
  const int rbase = bm * 128 + wr + kg * 4;
  const int cbase = bn * 128 + wc + la;
#pragma unroll
  for (int i = 0; i < 4; ++i) {
#pragma unroll
    for (int j = 0; j < 4; ++j) {
      int col = cbase + j * 16;
      float bv = bias[col];
#pragma unroll
      for (int e = 0; e < 4; ++e) {
        int row = rbase + i * 16 + e;
        float v = acc[i][j][e] + bv;
        if (MODE == 0) {
          ((float*)Cout)[(size_t)row * N + col] = v;
        } else {
          int tt = row & 511, bb = row >> 9;
          ((u16*)Cout)[((size_t)(tt * 32 + bb)) * N + col] = f2b(v);
        }
      }
    }
  }
}

// ---------------- fused two-layer persistent GRU recurrence, v4 ----------------
// 256 blocks x 256 threads (4 waves): layer = bid>>7, rt=(bid>>6)&1, colT=bid&63.
// Stage1: waves {0,2} = z, waves {1,3} = r. L0: K-split; L1: w0/w1 recurrent
//   (LDSh), w2/w3 x-projection of h0(t) (LDSx). Waves 2-3 drop partials;
//   wave0 finalizes z, wave1 finalizes r (coalesced publish + drain + fl1).
// Stage2: g split 4 ways; wave0 finalizes h (coalesced publish + fl2).
// Publishes: 16x16 u16 tile -> tbuf (LDS) -> per-lane 8B dwordx2 agent store.
// Ring: layer0 h -> hring[4]; fl2(L0) is the cross-layer flag; layer0 gates
//   on fl1(L1) >= t-3 so a slot is never overwritten early.

__global__ __launch_bounds__(256, 1) void gru_pipe4(
    const u16* __restrict__ Wz0, const u16* __restrict__ Wr0, const u16* __restrict__ Wg0,
    const u16* __restrict__ Wz1, const u16* __restrict__ Wr1, const u16* __restrict__ Wg1,
    const u16* __restrict__ Wzx1, const u16* __restrict__ Wrx1, const u16* __restrict__ Wgx1,
    const float* __restrict__ bz1, const float* __restrict__ br1, const float* __restrict__ bg1,
    const u16* __restrict__ Az, const u16* __restrict__ Ar, const u16* __restrict__ Ag,
    u16* __restrict__ hring, u16* __restrict__ hist1,
    float* __restrict__ h32_0, float* __restrict__ h32_1,
    u16* __restrict__ hbf1,
    u16* __restrict__ rhbf0, u16* __restrict__ rhbf1,
    u16* __restrict__ flags, int S) {
  __shared__ __align__(16) u16 LDSh[16 * 1024];
  __shared__ __align__(16) u16 LDSx[16 * 1024];
  __shared__ float part[4][256];
  __shared__ float zloc[256];
  __shared__ float h32loc[256];
  __shared__ __align__(8) u16 tbuf[2][256];  // 16x16 publish transpose tiles
  const int tid = threadIdx.x, wave = tid >> 6, lane = tid & 63;
  const int la = lane & 15, kg = lane >> 4;
  const int sw = la & 7;
  const int layer = blockIdx.x >> 7;
  const int rt = (blockIdx.x >> 6) & 1, colT = blockIdx.x & 63;
  const int col = colT * 16 + la;
  u16* myfl1 = flags + (layer * 2 + rt) * 128;  // stage1 (rhbf ready)
  u16* myfl2 = myfl1 + 64;                      // stage2 (h ready)
  u16* l1fl1 = flags + (2 + rt) * 128;          // layer1 stage1 (ring consumed)
  u16* l0fl2 = flags + rt * 128 + 64;           // layer0 h ready

  float* h32g = layer ? h32_1 : h32_0;
  u16* rhbf = layer ? rhbf1 : rhbf0;

  h32loc[tid] = h32g[(rt * 16 + (tid >> 4)) * 1024 + colT * 16 + (tid & 15)];

  // transpose-store lane mapping: lane -> (row, col-quad) of the 16x16 tile
  const int tr = lane >> 2, tq = lane & 3;

  // ---- stage-1 weights -> VGPRs ----
  bf16x8 wzr[32];
  if (layer) {
    const u16* wsrc;
    if (wave == 0) wsrc = Wz1;
    else if (wave == 1) wsrc = Wr1;
    else if (wave == 2) wsrc = Wzx1;
    else wsrc = Wrx1;
    const u16* wp = wsrc + (size_t)col * 1024 + kg * 8;
#pragma unroll
    for (int ks = 0; ks < 32; ++ks) wzr[ks] = ld8(wp + ks * 32);
  } else {
    const u16* wsrc = (wave & 1) ? Wr0 : Wz0;
    const u16* wp = wsrc + (size_t)col * 1024 + kg * 8 + (size_t)(wave >> 1) * 512;
#pragma unroll
    for (int ks = 0; ks < 16; ++ks) wzr[ks] = ld8(wp + ks * 32);
  }
  // ---- stage-2 weights -> VGPRs ----
  bf16x8 wg[16];
  if (layer) {
    const u16* wsrc = (wave < 2) ? Wg1 : Wgx1;
    const u16* wp = wsrc + (size_t)col * 1024 + kg * 8 + (size_t)(wave & 1) * 512;
#pragma unroll
    for (int ks = 0; ks < 16; ++ks) wg[ks] = ld8(wp + ks * 32);
  } else {
    const u16* wp = Wg0 + (size_t)col * 1024 + kg * 8 + (size_t)wave * 256;
#pragma unroll
    for (int ks = 0; ks < 8; ++ks) wg[ks] = ld8(wp + ks * 32);
  }
  float b1v = 0.f, bgv = 0.f;
  if (layer) {
    if (wave == 0) { b1v = bz1[col]; bgv = bg1[col]; }
    else if (wave == 1) b1v = br1[col];
  }
  __syncthreads();  // h32loc staged

  const u16* A1 = (wave == 1) ? Ar : Az;
  const u16* rsrc = rhbf + rt * 16384;
  const int rowb = rt * 16 + kg * 4;  // batch-row base of this lane's outputs

  for (int t = 0; t < S; ++t) {
    u16 a1raw[4] = {0, 0, 0, 0};
    u16 agraw[4] = {0, 0, 0, 0};
    if (!layer) {
      // A prefetch: independent of flags, overlaps poll+staging
      if (wave < 2) {
        const u16* A1t = A1 + (size_t)t * 32768;
#pragma unroll
        for (int e = 0; e < 4; ++e) a1raw[e] = A1t[(rowb + e) * 1024 + col];
      }
      if (wave == 0) {
        const u16* Agt = Ag + (size_t)t * 32768;
#pragma unroll
        for (int e = 0; e < 4; ++e) agraw[e] = Agt[(rowb + e) * 1024 + col];
      }
      // own h(t-1) ready + ring slot t&3 free (layer1 staged step t-4)
      unsigned tb = t >= 4 ? (unsigned)(t - 3) : 0u;
      poll64x2(myfl2, (unsigned)t, l1fl1, tb, lane);
    } else {
      // h1(t-1) ready + h0(t) ready; then both tiles' DMAs back-to-back
      poll64x2(myfl2, (unsigned)t, l0fl2, (unsigned)(t + 1), lane);
      const u16* xs = hring + (t & 3) * 32768 + rt * 16384;
#pragma unroll
      for (int i = 0; i < 8; ++i) {
        int u = i * 4 + wave, r = u >> 1, c = u & 1;
        gload_lds16c(xs + r * 1024 + c * 512 + (lane ^ (r & 7)) * 8,
                     LDSx + r * 1024 + c * 512 + lane * 8);
      }
    }
    // ---- stage 1 staging: h(t-1) -> LDSh (all 4 waves) ----
    const u16* hs = layer ? (hbf1 + rt * 16384)
                          : (hring + ((t + 3) & 3) * 32768 + rt * 16384);
#pragma unroll
    for (int i = 0; i < 8; ++i) {
      int u = i * 4 + wave, r = u >> 1, c = u & 1;
      gload_lds16c(hs + r * 1024 + c * 512 + (lane ^ (r & 7)) * 8,
                   LDSh + r * 1024 + c * 512 + lane * 8);
    }
    __syncthreads();  // B1: all DMA drained
    // ---- stage 1 MFMA ----
    f32x4 p0 = {0.f, 0.f, 0.f, 0.f}, p1 = {0.f, 0.f, 0.f, 0.f};
    if (layer) {
      const u16* aB = (wave >= 2) ? LDSx : LDSh;
#pragma unroll
      for (int ks = 0; ks < 32; ks += 2) {
        p0 = mfma16(ld8(aB + la * 1024 + (((ks * 4 + kg) ^ sw) << 3)), wzr[ks], p0);
        p1 = mfma16(ld8(aB + la * 1024 + ((((ks + 1) * 4 + kg) ^ sw) << 3)), wzr[ks + 1], p1);
      }
    } else {
      const int ko = (wave >> 1) * 16;
#pragma unroll
      for (int ks = 0; ks < 16; ks += 2) {
        p0 = mfma16(ld8(LDSh + la * 1024 + ((((ko + ks) * 4 + kg) ^ sw) << 3)), wzr[ks], p0);
        p1 = mfma16(ld8(LDSh + la * 1024 + ((((ko + ks + 1) * 4 + kg) ^ sw) << 3)), wzr[ks + 1], p1);
      }
    }
    if (wave >= 2) {
#pragma unroll
      for (int e = 0; e < 4; ++e) part[wave][lane * 4 + e] = p0[e] + p1[e];
    }
    __syncthreads();  // B2: stage1 partials visible; all LDSh reads done
    if (wave == 0) {
#pragma unroll
      for (int e = 0; e < 4; ++e) {
        float pre = p0[e] + p1[e] + part[2][lane * 4 + e] +
                    (layer ? b1v : b2f(a1raw[e]));
        zloc[(kg * 4 + e) * 16 + la] = 1.f / (1.f + __expf(-pre));
      }
    } else if (wave == 1) {
#pragma unroll
      for (int e = 0; e < 4; ++e) {
        float pre = p0[e] + p1[e] + part[3][lane * 4 + e] +
                    (layer ? b1v : b2f(a1raw[e]));
        float rv = 1.f / (1.f + __expf(-pre));
        tbuf[0][(kg * 4 + e) * 16 + la] =
            f2b(rv * h32loc[(kg * 4 + e) * 16 + la]);
      }
      __asm__ volatile("s_waitcnt lgkmcnt(0)" ::: "memory");
      {  // coalesced publish: one 8B agent store per lane (16 lines total)
        u64 v = *reinterpret_cast<u64*>(&tbuf[0][tr * 16 + tq * 4]);
        st64((u64*)&rhbf[(rt * 16 + tr) * 1024 + colT * 16 + tq * 4], v);
      }
      __builtin_amdgcn_s_waitcnt(0);  // r-tile drained to LLC
      if (lane == 0) st16(&myfl1[colT], (u16)(t + 1));
    }
    // ---- stage 2: rh -> LDSh, then g (4-way split) + h update ----
    poll64(myfl1, (unsigned)(t + 1), lane);
#pragma unroll
    for (int i = 0; i < 8; ++i) {
      int u = i * 4 + wave, r = u >> 1, c = u & 1;
      gload_lds16c(rsrc + r * 1024 + c * 512 + (lane ^ (r & 7)) * 8,
                   LDSh + r * 1024 + c * 512 + lane * 8);
    }
    __syncthreads();  // B3: rh staged (LDSx untouched, still h0(t))
    f32x4 q0 = {0.f, 0.f, 0.f, 0.f}, q1 = {0.f, 0.f, 0.f, 0.f};
    if (layer) {
      const u16* aB = (wave >= 2) ? LDSx : LDSh;
      const int ko = (wave & 1) * 16;
#pragma unroll
      for (int ks = 0; ks < 16; ks += 2) {
        q0 = mfma16(ld8(aB + la * 1024 + ((((ko + ks) * 4 + kg) ^ sw) << 3)), wg[ks], q0);
        q1 = mfma16(ld8(aB + la * 1024 + ((((ko + ks + 1) * 4 + kg) ^ sw) << 3)), wg[ks + 1], q1);
      }
    } else {
      const int ko = wave * 8;
#pragma unroll
      for (int ks = 0; ks < 8; ks += 2) {
        q0 = mfma16(ld8(LDSh + la * 1024 + ((((ko + ks) * 4 + kg) ^ sw) << 3)), wg[ks], q0);
        q1 = mfma16(ld8(LDSh + la * 1024 + ((((ko + ks + 1) * 4 + kg) ^ sw) << 3)), wg[ks + 1], q1);
      }
    }
    if (wave != 0) {
#pragma unroll
      for (int e = 0; e < 4; ++e) part[wave][lane * 4 + e] = q0[e] + q1[e];
    }
    __syncthreads();  // B4: stage2 partials visible; all LDSh/LDSx reads done
    if (wave == 0) {
      float hnv[4];
      u16* hdst = layer ? hbf1 : (hring + (t & 3) * 32768);
#pragma unroll
      for (int e = 0; e < 4; ++e) {
        int li = (kg * 4 + e) * 16 + la;
        int pi = lane * 4 + e;
        float gs = q0[e] + q1[e] + part[1][pi] + part[2][pi] + part[3][pi] +
                   (layer ? bgv : b2f(agraw[e]));
        float ex = __expf(2.f * gs);
        float g = 1.f - 2.f / (ex + 1.f);  // tanh, inf-safe
        float z = zloc[li];
        float hn = (1.f - z) * h32loc[li] + z * g;
        h32loc[li] = hn;
        hnv[e] = hn;
        tbuf[1][li] = f2b(hn);
      }
      __asm__ volatile("s_waitcnt lgkmcnt(0)" ::: "memory");
      u64 v = *reinterpret_cast<u64*>(&tbuf[1][tr * 16 + tq * 4]);
      st64((u64*)&hdst[(rt * 16 + tr) * 1024 + colT * 16 + tq * 4], v);
      __builtin_amdgcn_s_waitcnt(0);  // h-tile drained to LLC
      if (lane == 0) st16(&myfl2[colT], (u16)(t + 1));
      // off-critical-path: layer1 history (coalesced; read only by the output
      // GEMM, kernel-boundary flush gives visibility) + final-state snapshot
      if (layer)
        *reinterpret_cast<u64*>(
            &hist1[((size_t)(rt * 16 + tr) * S + t) * 1024 + colT * 16 + tq * 4]) = v;
      if (t == S - 1) {
#pragma unroll
        for (int e = 0; e < 4; ++e)
          h32g[(rowb + e) * 1024 + col] = hnv[e];
      }
    }
    // no loop-bottom barrier: next-step staging is gated by poll(myfl2 >= t+1),
    // which wave0 publishes only after all its LDS reads of this step.
  }
}

// ---------------- host ----------------

extern "C" void kernel_launch(void* const* d_in, const int* in_sizes, int n_in,
                              void* d_out, int out_size, void* d_ws, size_t ws_size,
                              hipStream_t stream) {
  (void)in_sizes; (void)n_in; (void)out_size;
  const float* x   = (const float*)d_in[0];
  const float* h0  = (const float*)d_in[1];
  const float* Wzx = (const float*)d_in[2];
  const float* bz  = (const float*)d_in[3];
  const float* Wzh = (const float*)d_in[4];
  const float* Wrx = (const float*)d_in[5];
  const float* br  = (const float*)d_in[6];
  const float* Wrh = (const float*)d_in[7];
  const float* Wgx = (const float*)d_in[8];
  const float* bg  = (const float*)d_in[9];
  const float* Wgh = (const float*)d_in[10];
  const float* Wo  = (const float*)d_in[11];
  const float* bo  = (const float*)d_in[12];
  float* out = (float*)d_out;
  char* ws = (char*)d_ws;

  const size_t MB = 1024 * 1024;
  size_t o = 4096;  // u16 epoch flags live in [0,4096)
  u16* wWzx = (u16*)(ws + o); o += 4 * MB;   // [L=2][1024][1024] bf16
  u16* wWzh = (u16*)(ws + o); o += 4 * MB;
  u16* wWrx = (u16*)(ws + o); o += 4 * MB;
  u16* wWrh = (u16*)(ws + o); o += 4 * MB;
  u16* wWgx = (u16*)(ws + o); o += 4 * MB;
  u16* wWgh = (u16*)(ws + o); o += 4 * MB;
  u16* wWo  = (u16*)(ws + o); o += 2 * MB;
  u16* Az    = (u16*)(ws + o); o += 32 * MB;  // [512][32][1024] bf16 step-major
  u16* Ar    = (u16*)(ws + o); o += 32 * MB;
  u16* Ag    = (u16*)(ws + o); o += 32 * MB;
  u16* hring = (u16*)(ws + o); o += 256 * 1024;  // [4][32][1024] layer0 h ring
  u16* xbf   = (u16*)(ws + o); o += 32 * MB;  // x bf16; later reused as hist1
  float* h32_0 = (float*)(ws + o); o += 131072;
  float* h32_1 = (float*)(ws + o); o += 131072;
  u16* hbf_1 = (u16*)(ws + o); o += 65536;
  u16* rhbf0 = (u16*)(ws + o); o += 65536;
  u16* rhbf1 = (u16*)(ws + o); o += 65536;

  if (ws_size < o) {
    fprintf(stderr, "[gru] INSUFFICIENT WORKSPACE ws=%zu need=%zu\n", ws_size, o);
    return;
  }
  u16* flags = (u16*)ws;
  hipMemsetAsync(ws, 0, 4096, stream);

  // casts
  castk<<<dim3(8192), dim3(256), 0, stream>>>(Wzx, wWzx, 2097152);
  castk<<<dim3(8192), dim3(256), 0, stream>>>(Wzh, wWzh, 2097152);
  castk<<<dim3(8192), dim3(256), 0, stream>>>(Wrx, wWrx, 2097152);
  castk<<<dim3(8192), dim3(256), 0, stream>>>(Wrh, wWrh, 2097152);
  castk<<<dim3(8192), dim3(256), 0, stream>>>(Wgx, wWgx, 2097152);
  castk<<<dim3(8192), dim3(256), 0, stream>>>(Wgh, wWgh, 2097152);
  castk<<<dim3(4096), dim3(256), 0, stream>>>(Wo, wWo, 1048576);
  castk<<<dim3(65536), dim3(256), 0, stream>>>(x, xbf, 16777216);
  init_h<<<dim3(128), dim3(256), 0, stream>>>(h0, h32_0, h32_1,
                                              hring + 3 * 32768, hbf_1);

  // layer0 input projections (step-major output)
  gemm_nt<2><<<dim3(1024), dim3(256), 0, stream>>>(xbf, wWzx, bz, Az, 16384, 1024, 1024);
  gemm_nt<2><<<dim3(1024), dim3(256), 0, stream>>>(xbf, wWrx, br, Ar, 16384, 1024, 1024);
  gemm_nt<2><<<dim3(1024), dim3(256), 0, stream>>>(xbf, wWgx, bg, Ag, 16384, 1024, 1024);

  // fused two-layer recurrence pipeline (hist1 lives in xbf region)
  gru_pipe4<<<dim3(256), dim3(256), 0, stream>>>(
      wWzh, wWrh, wWgh,
      wWzh + 1048576, wWrh + 1048576, wWgh + 1048576,
      wWzx + 1048576, wWrx + 1048576, wWgx + 1048576,
      bz + 1024, br + 1024, bg + 1024,
      Az, Ar, Ag, hring, xbf,
      h32_0, h32_1, hbf_1, rhbf0, rhbf1,
      flags, 512);

  // output projection
  gemm_nt<0><<<dim3(1024), dim3(256), 0, stream>>>(xbf, wWo, bo, out, 16384, 1024, 1024);

  // final hidden states
  final_h<<<dim3(128), dim3(256), 0, stream>>>(h32_0, h32_1, out + 16777216);
}